// Round 19
// baseline (175.878 us; speedup 1.0000x reference)
//
#include <hip/hip_runtime.h>
#include <hip/hip_bf16.h>

#define N_NODES 80000
#define N_EDGES 1280000
#define N_FEAT 4
#define HIDDEN 64
#define N_GRAPHS 64
#define BN_EPS 1e-5f

#define NBUCK 313          // ceil(80000 / 256); bucket b covers nodes [b*256, b*256+256)
#define BCAP 8000          // per-bucket capacity (mean 4090, sigma ~64 -> safe)

typedef unsigned short ushort_t;
typedef __attribute__((ext_vector_type(8))) short bf16x8;
typedef __attribute__((ext_vector_type(4))) float f32x4;

__device__ __forceinline__ float bf2f(ushort_t v) {
    return __uint_as_float(((unsigned)v) << 16);
}
__device__ __forceinline__ ushort_t f2bf(float f) {
    unsigned u = __float_as_uint(f);
    u += 0x7FFFu + ((u >> 16) & 1u);
    return (ushort_t)(u >> 16);
}

// ---------------------------------------------------------------------------
// Weight prep (layers 2+3) + zero-init of bcursor/pool/cnt
__global__ void wprep_kernel(const float* __restrict__ W2_rel,
                             const float* __restrict__ W2_root,
                             const float* __restrict__ W3_rel,
                             const float* __restrict__ W3_root,
                             ushort_t* __restrict__ WcatT2,
                             ushort_t* __restrict__ WcatT3,
                             int* __restrict__ bcursor,
                             float* __restrict__ pool,
                             float* __restrict__ cnt) {
    int i = blockIdx.x * blockDim.x + threadIdx.x;   // 64*256 = 16384 = 2*8192
    int which = i >= 64 * 128;
    int j = i & (64 * 128 - 1);
    int n = j >> 7, k = j & 127;
    const float* Wr = which ? W3_rel : W2_rel;
    const float* Wo = which ? W3_root : W2_root;
    ushort_t* Wc = which ? WcatT3 : WcatT2;
    float w = (k < 64) ? Wr[k * 64 + n] : Wo[(k - 64) * 64 + n];
    Wc[j] = f2bf(w);
    if (i < 4096) pool[i] = 0.f;
    else if (i < 4160) cnt[i - 4096] = 0.f;
    else if (i < 4160 + NBUCK) bcursor[i - 4160] = 0;
}

// ---------------------------------------------------------------------------
// Bucketed counting sort (r13: int4 vectorized edge loads; packed pairs)
__global__ __launch_bounds__(256) void bucket_kernel(
        const int* __restrict__ src, const int* __restrict__ dst,
        unsigned* __restrict__ pairs, int* __restrict__ bcursor) {
    __shared__ int hist[NBUCK];
    __shared__ int base[NBUCK];
    for (int i = threadIdx.x; i < NBUCK; i += 256) hist[i] = 0;
    __syncthreads();
    int d[16], r[16];
#pragma unroll
    for (int g = 0; g < 4; ++g) {
        int e = blockIdx.x * 4096 + g * 1024 + threadIdx.x * 4;
        if (e + 4 <= N_EDGES) {
            int4 dd = *(const int4*)&dst[e];
            d[g * 4 + 0] = dd.x; d[g * 4 + 1] = dd.y;
            d[g * 4 + 2] = dd.z; d[g * 4 + 3] = dd.w;
            r[g * 4 + 0] = atomicAdd(&hist[dd.x >> 8], 1);
            r[g * 4 + 1] = atomicAdd(&hist[dd.y >> 8], 1);
            r[g * 4 + 2] = atomicAdd(&hist[dd.z >> 8], 1);
            r[g * 4 + 3] = atomicAdd(&hist[dd.w >> 8], 1);
        } else {
            d[g * 4] = -1;
        }
    }
    __syncthreads();
    for (int i = threadIdx.x; i < NBUCK; i += 256) {
        int c = hist[i];
        base[i] = c ? atomicAdd(&bcursor[i], c) : 0;
    }
    __syncthreads();
#pragma unroll
    for (int g = 0; g < 4; ++g) {
        int e = blockIdx.x * 4096 + g * 1024 + threadIdx.x * 4;
        if (e + 4 <= N_EDGES) {
            int4 ss = *(const int4*)&src[e];
            int sv[4] = {ss.x, ss.y, ss.z, ss.w};
#pragma unroll
            for (int k = 0; k < 4; ++k) {
                int dk = d[g * 4 + k];
                int b = dk >> 8;
                int pos = base[b] + r[g * 4 + k];
                if (pos < BCAP)
                    pairs[(size_t)b * BCAP + pos] =
                        (unsigned)sv[k] | (((unsigned)dk & 255u) << 17);
            }
        }
    }
}

// ---------------------------------------------------------------------------
// csr_build (r13: uint4 pair reads; inline base computation)
__global__ __launch_bounds__(256) void csr_build_kernel(
        const unsigned* __restrict__ pairs, const int* __restrict__ bcursor,
        int* __restrict__ rowstart, int* __restrict__ csr) {
    __shared__ int degl[256];
    __shared__ int pref[256];
    __shared__ int curs[256];
    const int b = blockIdx.x;
    const int t = threadIdx.x;
    int partial = 0;
    for (int i = t; i < b; i += 256) partial += min(bcursor[i], BCAP);
    pref[t] = partial;
    __syncthreads();
    for (int off = 128; off > 0; off >>= 1) {
        if (t < off) pref[t] += pref[t + off];
        __syncthreads();
    }
    const int base = pref[0];
    const int cntb = min(bcursor[b], BCAP);
    __syncthreads();
    degl[t] = 0;
    __syncthreads();
    const unsigned* pb = pairs + (size_t)b * BCAP;
    for (int i = t * 4; i < cntb; i += 1024) {
        if (i + 4 <= cntb) {
            uint4 p4 = *(const uint4*)&pb[i];
            atomicAdd(&degl[p4.x >> 17], 1);
            atomicAdd(&degl[p4.y >> 17], 1);
            atomicAdd(&degl[p4.z >> 17], 1);
            atomicAdd(&degl[p4.w >> 17], 1);
        } else {
            for (int k = i; k < cntb; ++k) atomicAdd(&degl[pb[k] >> 17], 1);
        }
    }
    __syncthreads();
    int v = degl[t];
    pref[t] = v;
    __syncthreads();
    for (int off = 1; off < 256; off <<= 1) {
        int u = (t >= off) ? pref[t - off] : 0;
        __syncthreads();
        pref[t] += u;
        __syncthreads();
    }
    int excl = pref[t] - v;
    int node = b * 256 + t;
    if (node < N_NODES) rowstart[node] = base + excl;
    if (b == NBUCK - 1 && t == 255) rowstart[N_NODES] = base + cntb;
    curs[t] = excl;
    __syncthreads();
    for (int i = t * 4; i < cntb; i += 1024) {
        if (i + 4 <= cntb) {
            uint4 p4 = *(const uint4*)&pb[i];
            unsigned pv[4] = {p4.x, p4.y, p4.z, p4.w};
#pragma unroll
            for (int k = 0; k < 4; ++k) {
                int pos = atomicAdd(&curs[pv[k] >> 17], 1);
                csr[base + pos] = (int)(pv[k] & 0x1FFFFu);
            }
        } else {
            for (int k = i; k < cntb; ++k) {
                unsigned p = pb[k];
                int pos = atomicAdd(&curs[p >> 17], 1);
                csr[base + pos] = (int)(p & 0x1FFFFu);
            }
        }
    }
}

// ---------------------------------------------------------------------------
// Layer 1 (in=4, out=64), BN folded — grid-stride (r13 form).
__global__ __launch_bounds__(1024) void layer1_kernel(
        const float* __restrict__ x, ushort_t* __restrict__ h1,
        const int* __restrict__ rowstart, const int* __restrict__ csr,
        const float* __restrict__ Wrel, const float* __restrict__ Wroot,
        const float* __restrict__ b,
        const float* __restrict__ gamma, const float* __restrict__ beta,
        const float* __restrict__ mean, const float* __restrict__ var) {
    const int lane = threadIdx.x & 63;
    const int wid = threadIdx.x >> 6;
    float scale[4], shift[4];
#pragma unroll
    for (int k = 0; k < 4; ++k) {
        float sc = gamma[k] * rsqrtf(var[k] + BN_EPS);
        scale[k] = sc;
        shift[k] = beta[k] - mean[k] * sc;
    }
    float wrel2[4], wroot2[4];
    float crel = 0.f, croot = 0.f;
#pragma unroll
    for (int k = 0; k < 4; ++k) {
        float wr = Wrel[k * 64 + lane], wo = Wroot[k * 64 + lane];
        wrel2[k] = scale[k] * wr;  crel += shift[k] * wr;
        wroot2[k] = scale[k] * wo; croot += shift[k] * wo;
    }
    const float bj = b[lane] + croot;
    const int sub = lane >> 2;
    const int f = lane & 3;
    const int nW = gridDim.x * 16;
    for (int n0 = blockIdx.x * 16 + wid; n0 < N_NODES; n0 += nW) {
        const int node = __builtin_amdgcn_readfirstlane(n0);
        const int e0 = rowstart[node], e1 = rowstart[node + 1];
        const float deg = (float)(e1 - e0);
        float part = 0.f;
        for (int e = e0 + sub; e < e1; e += 16) {
            int s = csr[e];
            part += x[s * 4 + f];
        }
        part += __shfl_xor(part, 4);
        part += __shfl_xor(part, 8);
        part += __shfl_xor(part, 16);
        part += __shfl_xor(part, 32);
        float a0 = __shfl(part, 0), a1 = __shfl(part, 1);
        float a2 = __shfl(part, 2), a3 = __shfl(part, 3);
        float x0 = x[node * 4 + 0], x1 = x[node * 4 + 1];
        float x2 = x[node * 4 + 2], x3 = x[node * 4 + 3];
        float out = bj + deg * crel
                  + a0 * wrel2[0] + a1 * wrel2[1] + a2 * wrel2[2] + a3 * wrel2[3]
                  + x0 * wroot2[0] + x1 * wroot2[1] + x2 * wroot2[2] + x3 * wroot2[3];
        h1[(size_t)node * 64 + lane] = f2bf(fmaxf(out, 0.f));
    }
}

// ---------------------------------------------------------------------------
// Fused layer v4 (r18): r15 structure (256 thr, 4 waves x 4 serial nodes),
// but the gather uses ONE 64-wide idx load per node (covers deg<=64, i.e.
// virtually all nodes at Poisson(16)) -> per-node dependent chain halves
// vs r15's main+tail idx loads, at +1 VGPR (occupancy preserved).
__global__ __launch_bounds__(256) void fused_layer_kernel(
        const ushort_t* __restrict__ hin, ushort_t* __restrict__ hout,
        const int* __restrict__ rowstart, const int* __restrict__ csr,
        const ushort_t* __restrict__ WcatT, const float* __restrict__ b,
        int relu) {
    __shared__ ushort_t As[16][72];   // agg rows; stride 144B -> bank-spread
    const int lane = threadIdx.x & 63;
    const int wid = threadIdx.x >> 6;
    const int l4 = lane & 15;             // feature quad
    const int q = lane >> 4;              // edge sub-slot 0..3
    const int node0 = blockIdx.x * 16;

    // ---- gather phase: wave wid owns rows wid*4 .. wid*4+3 ----
    for (int i = 0; i < 4; ++i) {
        const int row = wid * 4 + i;
        const int node = __builtin_amdgcn_readfirstlane(node0 + row);
        const int e0 = rowstart[node], e1 = rowstart[node + 1];
        float ax[4] = {0.f, 0.f, 0.f, 0.f}, ay[4] = {0.f, 0.f, 0.f, 0.f};
        float az[4] = {0.f, 0.f, 0.f, 0.f}, aw[4] = {0.f, 0.f, 0.f, 0.f};
        for (int e = e0; e < e1; e += 64) {       // one 64-edge super-step (deg<=64: once)
            const int nE = min(e1 - e, 64);       // uniform scalar
            int idx64 = csr[min(e + lane, e1 - 1)];  // ONE 256B idx load
#pragma unroll
            for (int g = 0; g < 4; ++g) {
                if (g * 16 >= nE) break;          // uniform scalar branch
                const int rem = nE - g * 16;
                if (rem >= 16) {
#pragma unroll
                    for (int j = 0; j < 4; ++j) {
                        int s = __shfl(idx64, g * 16 + 4 * j + q);
                        uint2 rp = *(const uint2*)&hin[(size_t)s * 64 + 4 * l4];
                        ax[j] += __uint_as_float(rp.x << 16);
                        ay[j] += __uint_as_float(rp.x & 0xFFFF0000u);
                        az[j] += __uint_as_float(rp.y << 16);
                        aw[j] += __uint_as_float(rp.y & 0xFFFF0000u);
                    }
                } else {
#pragma unroll
                    for (int j = 0; j < 4; ++j) {
                        int slot = 4 * j + q;
                        int s = __shfl(idx64, g * 16 + min(slot, rem - 1));
                        uint2 rp = *(const uint2*)&hin[(size_t)s * 64 + 4 * l4];
                        bool ok = slot < rem;
                        ax[j] += ok ? __uint_as_float(rp.x << 16) : 0.f;
                        ay[j] += ok ? __uint_as_float(rp.x & 0xFFFF0000u) : 0.f;
                        az[j] += ok ? __uint_as_float(rp.y << 16) : 0.f;
                        aw[j] += ok ? __uint_as_float(rp.y & 0xFFFF0000u) : 0.f;
                    }
                }
            }
        }
        float fx = (ax[0] + ax[1]) + (ax[2] + ax[3]);
        float fy = (ay[0] + ay[1]) + (ay[2] + ay[3]);
        float fz = (az[0] + az[1]) + (az[2] + az[3]);
        float fw = (aw[0] + aw[1]) + (aw[2] + aw[3]);
        fx += __shfl_xor(fx, 16); fx += __shfl_xor(fx, 32);
        fy += __shfl_xor(fy, 16); fy += __shfl_xor(fy, 32);
        fz += __shfl_xor(fz, 16); fz += __shfl_xor(fz, 32);
        fw += __shfl_xor(fw, 16); fw += __shfl_xor(fw, 32);
        if (lane < 16) {
            uint2 ap;
            ap.x = (unsigned)f2bf(fx) | ((unsigned)f2bf(fy) << 16);
            ap.y = (unsigned)f2bf(fz) | ((unsigned)f2bf(fw) << 16);
            *(uint2*)&As[row][l4 * 4] = ap;
        }
    }
    __syncthreads();

    // ---- GEMM phase: wave wid computes slab nt = wid (cols wid*16..+15) ----
    const int col = lane & 15;
    const int grp = lane >> 4;
    bf16x8 bf[4];
#pragma unroll
    for (int kt = 0; kt < 4; ++kt)
        bf[kt] = *(const bf16x8*)&WcatT[(wid * 16 + col) * 128 + kt * 32 + grp * 8];
    const float bj = b[wid * 16 + col];

    const ushort_t* ha = hin + (size_t)(node0 + col) * 64 + grp * 8;
    f32x4 acc = {0.f, 0.f, 0.f, 0.f};
#pragma unroll
    for (int kt = 0; kt < 4; ++kt) {
        bf16x8 a = (kt < 2) ? *(const bf16x8*)&As[col][kt * 32 + grp * 8]
                            : *(const bf16x8*)(ha + (kt - 2) * 32);
        acc = __builtin_amdgcn_mfma_f32_16x16x32_bf16(a, bf[kt], acc, 0, 0, 0);
    }
    const int c = wid * 16 + col;
#pragma unroll
    for (int r = 0; r < 4; ++r) {
        int row = grp * 4 + r;
        float v = acc[r] + bj;
        if (relu) v = fmaxf(v, 0.f);
        hout[(size_t)(node0 + row) * 64 + c] = f2bf(v);
    }
}

// ---------------------------------------------------------------------------
// Mean-pool per graph (r10): 8-row unrolled loads.
__global__ void pool_kernel(const ushort_t* __restrict__ h3, const int* __restrict__ batch,
                            float* __restrict__ pool, float* __restrict__ cnt) {
    const int lane = threadIdx.x & 63;
    const int gw = (blockIdx.x * blockDim.x + threadIdx.x) >> 6;
    const int nW = (gridDim.x * blockDim.x) >> 6;
    const int chunk = (N_NODES + nW - 1) / nW;
    int n0 = gw * chunk;
    int n1 = n0 + chunk; if (n1 > N_NODES) n1 = N_NODES;
    if (n0 >= N_NODES) return;
    float acc = 0.f;
    int cur = batch[n0];
    int cl = 0;
#define POOL_FLUSH() do { atomicAdd(&pool[cur * 64 + lane], acc); \
        if (lane == 0) atomicAdd(&cnt[cur], (float)cl); acc = 0.f; cl = 0; } while (0)
    int n = n0;
    for (; n + 8 <= n1; n += 8) {
        float v0 = bf2f(h3[(size_t)(n + 0) * 64 + lane]);
        float v1 = bf2f(h3[(size_t)(n + 1) * 64 + lane]);
        float v2 = bf2f(h3[(size_t)(n + 2) * 64 + lane]);
        float v3 = bf2f(h3[(size_t)(n + 3) * 64 + lane]);
        float v4 = bf2f(h3[(size_t)(n + 4) * 64 + lane]);
        float v5 = bf2f(h3[(size_t)(n + 5) * 64 + lane]);
        float v6 = bf2f(h3[(size_t)(n + 6) * 64 + lane]);
        float v7 = bf2f(h3[(size_t)(n + 7) * 64 + lane]);
        int g0 = batch[n + 0], g1 = batch[n + 1], g2 = batch[n + 2], g3 = batch[n + 3];
        int g4 = batch[n + 4], g5 = batch[n + 5], g6 = batch[n + 6], g7 = batch[n + 7];
        if (g0 != cur) { POOL_FLUSH(); cur = g0; } acc += v0; cl++;
        if (g1 != cur) { POOL_FLUSH(); cur = g1; } acc += v1; cl++;
        if (g2 != cur) { POOL_FLUSH(); cur = g2; } acc += v2; cl++;
        if (g3 != cur) { POOL_FLUSH(); cur = g3; } acc += v3; cl++;
        if (g4 != cur) { POOL_FLUSH(); cur = g4; } acc += v4; cl++;
        if (g5 != cur) { POOL_FLUSH(); cur = g5; } acc += v5; cl++;
        if (g6 != cur) { POOL_FLUSH(); cur = g6; } acc += v6; cl++;
        if (g7 != cur) { POOL_FLUSH(); cur = g7; } acc += v7; cl++;
    }
    for (; n < n1; ++n) {
        int g = batch[n];
        if (g != cur) { POOL_FLUSH(); cur = g; }
        acc += bf2f(h3[(size_t)n * 64 + lane]);
        cl++;
    }
    atomicAdd(&pool[cur * 64 + lane], acc);
    if (lane == 0) atomicAdd(&cnt[cur], (float)cl);
#undef POOL_FLUSH
}

// Final head
__global__ void head_kernel(const float* __restrict__ pool, const float* __restrict__ cnt,
                            const float* __restrict__ linW, const float* __restrict__ linb,
                            float* __restrict__ out) {
    int g = threadIdx.x >> 1;
    int c = threadIdx.x & 1;
    if (g < N_GRAPHS) {
        float inv = 1.0f / fmaxf(cnt[g], 1.0f);
        float acc = linb[c];
        for (int j = 0; j < 64; ++j) acc += pool[g * 64 + j] * inv * linW[j * 2 + c];
        out[g * 2 + c] = acc;
    }
}

// ---------------------------------------------------------------------------
extern "C" void kernel_launch(void* const* d_in, const int* in_sizes, int n_in,
                              void* d_out, int out_size, void* d_ws, size_t ws_size,
                              hipStream_t stream) {
    const float* x = (const float*)d_in[0];
    const int* edge_index = (const int*)d_in[1];
    const int* batch = (const int*)d_in[2];
    const float* bn_gamma = (const float*)d_in[3];
    const float* bn_beta = (const float*)d_in[4];
    const float* bn_mean = (const float*)d_in[5];
    const float* bn_var = (const float*)d_in[6];
    const float* W1_rel = (const float*)d_in[7];
    const float* b1_rel = (const float*)d_in[8];
    const float* W1_root = (const float*)d_in[9];
    const float* W2_rel = (const float*)d_in[10];
    const float* b2_rel = (const float*)d_in[11];
    const float* W2_root = (const float*)d_in[12];
    const float* W3_rel = (const float*)d_in[13];
    const float* b3_rel = (const float*)d_in[14];
    const float* W3_root = (const float*)d_in[15];
    const float* lin_W = (const float*)d_in[16];
    const float* lin_b = (const float*)d_in[17];
    float* out = (float*)d_out;

    const int* e_src = edge_index;
    const int* e_dst = edge_index + N_EDGES;

    // workspace layout (16B-aligned sections)
    ushort_t* h1 = (ushort_t*)d_ws;             // 5.12M bf16 = 10.24MB
    ushort_t* h2 = h1 + 5120000;                // 5.12M bf16 = 10.24MB
    float* pool = (float*)(h2 + 5120000);       // 4096 f32
    float* cnt = pool + 4096;                   // 64
    int* bcursor = (int*)(cnt + 64);            // 320
    int* rowstart = bcursor + 640;              // 80016 (padded)
    int* csr = rowstart + 80016;                // 1280000
    ushort_t* WcatT2 = (ushort_t*)(csr + 1280000); // 8192 bf16
    ushort_t* WcatT3 = WcatT2 + 8192;              // 8192 bf16
    unsigned* pairs = (unsigned*)h1;            // NBUCK*BCAP*4B = 10.02MB <= h1
    ushort_t* h3 = h1;                          // alias: h1 dead once h2 computed

    // Weight prep + zero-init (bcursor/pool/cnt)
    wprep_kernel<<<64, 256, 0, stream>>>(W2_rel, W2_root, W3_rel, W3_root,
                                         WcatT2, WcatT3, bcursor, pool, cnt);

    // CSR build (bucketed counting sort; scan folded into csr_build)
    bucket_kernel<<<(N_EDGES + 4095) / 4096, 256, 0, stream>>>(
        e_src, e_dst, pairs, bcursor);
    csr_build_kernel<<<NBUCK, 256, 0, stream>>>(pairs, bcursor, rowstart, csr);

    // Layer 1 (BN folded, grid-stride): h1 = relu(conv(bn(x)))
    layer1_kernel<<<512, 1024, 0, stream>>>(x, h1, rowstart, csr, W1_rel, W1_root,
                                            b1_rel, bn_gamma, bn_beta, bn_mean, bn_var);

    // Layer 2 (fused gather+GEMM, 64-wide idx): h2 = relu(conv(h1))
    fused_layer_kernel<<<N_NODES / 16, 256, 0, stream>>>(
        h1, h2, rowstart, csr, WcatT2, b2_rel, 1);
    // Layer 3 (fused): h3 = conv(h2)   (h3 aliases h1)
    fused_layer_kernel<<<N_NODES / 16, 256, 0, stream>>>(
        h2, h3, rowstart, csr, WcatT3, b3_rel, 0);

    // Pool + head
    pool_kernel<<<256, 256, 0, stream>>>(h3, batch, pool, cnt);
    head_kernel<<<1, 128, 0, stream>>>(pool, cnt, lin_W, lin_b, out);
}

// Round 20
// 162.390 us; speedup vs baseline: 1.0831x; 1.0831x over previous
//
#include <hip/hip_runtime.h>
#include <hip/hip_bf16.h>

#define N_NODES 80000
#define N_EDGES 1280000
#define N_FEAT 4
#define HIDDEN 64
#define N_GRAPHS 64
#define BN_EPS 1e-5f

#define NBUCK 313          // ceil(80000 / 256); bucket b covers nodes [b*256, b*256+256)
#define BCAP 8000          // per-bucket capacity (mean 4090, sigma ~64 -> safe)

typedef unsigned short ushort_t;
typedef __attribute__((ext_vector_type(8))) short bf16x8;
typedef __attribute__((ext_vector_type(4))) float f32x4;

__device__ __forceinline__ float bf2f(ushort_t v) {
    return __uint_as_float(((unsigned)v) << 16);
}
__device__ __forceinline__ ushort_t f2bf(float f) {
    unsigned u = __float_as_uint(f);
    u += 0x7FFFu + ((u >> 16) & 1u);
    return (ushort_t)(u >> 16);
}

// ---------------------------------------------------------------------------
// Weight prep (layers 2+3) + zero-init of bcursor/pool/cnt
__global__ void wprep_kernel(const float* __restrict__ W2_rel,
                             const float* __restrict__ W2_root,
                             const float* __restrict__ W3_rel,
                             const float* __restrict__ W3_root,
                             ushort_t* __restrict__ WcatT2,
                             ushort_t* __restrict__ WcatT3,
                             int* __restrict__ bcursor,
                             float* __restrict__ pool,
                             float* __restrict__ cnt) {
    int i = blockIdx.x * blockDim.x + threadIdx.x;   // 64*256 = 16384 = 2*8192
    int which = i >= 64 * 128;
    int j = i & (64 * 128 - 1);
    int n = j >> 7, k = j & 127;
    const float* Wr = which ? W3_rel : W2_rel;
    const float* Wo = which ? W3_root : W2_root;
    ushort_t* Wc = which ? WcatT3 : WcatT2;
    float w = (k < 64) ? Wr[k * 64 + n] : Wo[(k - 64) * 64 + n];
    Wc[j] = f2bf(w);
    if (i < 4096) pool[i] = 0.f;
    else if (i < 4160) cnt[i - 4096] = 0.f;
    else if (i < 4160 + NBUCK) bcursor[i - 4160] = 0;
}

// ---------------------------------------------------------------------------
// Bucketed counting sort (r13: int4 vectorized edge loads; packed pairs)
__global__ __launch_bounds__(256) void bucket_kernel(
        const int* __restrict__ src, const int* __restrict__ dst,
        unsigned* __restrict__ pairs, int* __restrict__ bcursor) {
    __shared__ int hist[NBUCK];
    __shared__ int base[NBUCK];
    for (int i = threadIdx.x; i < NBUCK; i += 256) hist[i] = 0;
    __syncthreads();
    int d[16], r[16];
#pragma unroll
    for (int g = 0; g < 4; ++g) {
        int e = blockIdx.x * 4096 + g * 1024 + threadIdx.x * 4;
        if (e + 4 <= N_EDGES) {
            int4 dd = *(const int4*)&dst[e];
            d[g * 4 + 0] = dd.x; d[g * 4 + 1] = dd.y;
            d[g * 4 + 2] = dd.z; d[g * 4 + 3] = dd.w;
            r[g * 4 + 0] = atomicAdd(&hist[dd.x >> 8], 1);
            r[g * 4 + 1] = atomicAdd(&hist[dd.y >> 8], 1);
            r[g * 4 + 2] = atomicAdd(&hist[dd.z >> 8], 1);
            r[g * 4 + 3] = atomicAdd(&hist[dd.w >> 8], 1);
        } else {
            d[g * 4] = -1;
        }
    }
    __syncthreads();
    for (int i = threadIdx.x; i < NBUCK; i += 256) {
        int c = hist[i];
        base[i] = c ? atomicAdd(&bcursor[i], c) : 0;
    }
    __syncthreads();
#pragma unroll
    for (int g = 0; g < 4; ++g) {
        int e = blockIdx.x * 4096 + g * 1024 + threadIdx.x * 4;
        if (e + 4 <= N_EDGES) {
            int4 ss = *(const int4*)&src[e];
            int sv[4] = {ss.x, ss.y, ss.z, ss.w};
#pragma unroll
            for (int k = 0; k < 4; ++k) {
                int dk = d[g * 4 + k];
                int b = dk >> 8;
                int pos = base[b] + r[g * 4 + k];
                if (pos < BCAP)
                    pairs[(size_t)b * BCAP + pos] =
                        (unsigned)sv[k] | (((unsigned)dk & 255u) << 17);
            }
        }
    }
}

// ---------------------------------------------------------------------------
// csr_build (r13: uint4 pair reads; inline base computation)
__global__ __launch_bounds__(256) void csr_build_kernel(
        const unsigned* __restrict__ pairs, const int* __restrict__ bcursor,
        int* __restrict__ rowstart, int* __restrict__ csr) {
    __shared__ int degl[256];
    __shared__ int pref[256];
    __shared__ int curs[256];
    const int b = blockIdx.x;
    const int t = threadIdx.x;
    int partial = 0;
    for (int i = t; i < b; i += 256) partial += min(bcursor[i], BCAP);
    pref[t] = partial;
    __syncthreads();
    for (int off = 128; off > 0; off >>= 1) {
        if (t < off) pref[t] += pref[t + off];
        __syncthreads();
    }
    const int base = pref[0];
    const int cntb = min(bcursor[b], BCAP);
    __syncthreads();
    degl[t] = 0;
    __syncthreads();
    const unsigned* pb = pairs + (size_t)b * BCAP;
    for (int i = t * 4; i < cntb; i += 1024) {
        if (i + 4 <= cntb) {
            uint4 p4 = *(const uint4*)&pb[i];
            atomicAdd(&degl[p4.x >> 17], 1);
            atomicAdd(&degl[p4.y >> 17], 1);
            atomicAdd(&degl[p4.z >> 17], 1);
            atomicAdd(&degl[p4.w >> 17], 1);
        } else {
            for (int k = i; k < cntb; ++k) atomicAdd(&degl[pb[k] >> 17], 1);
        }
    }
    __syncthreads();
    int v = degl[t];
    pref[t] = v;
    __syncthreads();
    for (int off = 1; off < 256; off <<= 1) {
        int u = (t >= off) ? pref[t - off] : 0;
        __syncthreads();
        pref[t] += u;
        __syncthreads();
    }
    int excl = pref[t] - v;
    int node = b * 256 + t;
    if (node < N_NODES) rowstart[node] = base + excl;
    if (b == NBUCK - 1 && t == 255) rowstart[N_NODES] = base + cntb;
    curs[t] = excl;
    __syncthreads();
    for (int i = t * 4; i < cntb; i += 1024) {
        if (i + 4 <= cntb) {
            uint4 p4 = *(const uint4*)&pb[i];
            unsigned pv[4] = {p4.x, p4.y, p4.z, p4.w};
#pragma unroll
            for (int k = 0; k < 4; ++k) {
                int pos = atomicAdd(&curs[pv[k] >> 17], 1);
                csr[base + pos] = (int)(pv[k] & 0x1FFFFu);
            }
        } else {
            for (int k = i; k < cntb; ++k) {
                unsigned p = pb[k];
                int pos = atomicAdd(&curs[p >> 17], 1);
                csr[base + pos] = (int)(p & 0x1FFFFu);
            }
        }
    }
}

// ---------------------------------------------------------------------------
// Layer 1 (in=4, out=64), BN folded — grid-stride (r13 form).
__global__ __launch_bounds__(1024) void layer1_kernel(
        const float* __restrict__ x, ushort_t* __restrict__ h1,
        const int* __restrict__ rowstart, const int* __restrict__ csr,
        const float* __restrict__ Wrel, const float* __restrict__ Wroot,
        const float* __restrict__ b,
        const float* __restrict__ gamma, const float* __restrict__ beta,
        const float* __restrict__ mean, const float* __restrict__ var) {
    const int lane = threadIdx.x & 63;
    const int wid = threadIdx.x >> 6;
    float scale[4], shift[4];
#pragma unroll
    for (int k = 0; k < 4; ++k) {
        float sc = gamma[k] * rsqrtf(var[k] + BN_EPS);
        scale[k] = sc;
        shift[k] = beta[k] - mean[k] * sc;
    }
    float wrel2[4], wroot2[4];
    float crel = 0.f, croot = 0.f;
#pragma unroll
    for (int k = 0; k < 4; ++k) {
        float wr = Wrel[k * 64 + lane], wo = Wroot[k * 64 + lane];
        wrel2[k] = scale[k] * wr;  crel += shift[k] * wr;
        wroot2[k] = scale[k] * wo; croot += shift[k] * wo;
    }
    const float bj = b[lane] + croot;
    const int sub = lane >> 2;
    const int f = lane & 3;
    const int nW = gridDim.x * 16;
    for (int n0 = blockIdx.x * 16 + wid; n0 < N_NODES; n0 += nW) {
        const int node = __builtin_amdgcn_readfirstlane(n0);
        const int e0 = rowstart[node], e1 = rowstart[node + 1];
        const float deg = (float)(e1 - e0);
        float part = 0.f;
        for (int e = e0 + sub; e < e1; e += 16) {
            int s = csr[e];
            part += x[s * 4 + f];
        }
        part += __shfl_xor(part, 4);
        part += __shfl_xor(part, 8);
        part += __shfl_xor(part, 16);
        part += __shfl_xor(part, 32);
        float a0 = __shfl(part, 0), a1 = __shfl(part, 1);
        float a2 = __shfl(part, 2), a3 = __shfl(part, 3);
        float x0 = x[node * 4 + 0], x1 = x[node * 4 + 1];
        float x2 = x[node * 4 + 2], x3 = x[node * 4 + 3];
        float out = bj + deg * crel
                  + a0 * wrel2[0] + a1 * wrel2[1] + a2 * wrel2[2] + a3 * wrel2[3]
                  + x0 * wroot2[0] + x1 * wroot2[1] + x2 * wroot2[2] + x3 * wroot2[3];
        h1[(size_t)node * 64 + lane] = f2bf(fmaxf(out, 0.f));
    }
}

// ---------------------------------------------------------------------------
// Fused layer (r15 — session best): gather + MFMA transform in ONE kernel.
// Block = 16 nodes, 4 waves. Each wave gathers 4 nodes (dwordx2 rows,
// clamped tail) into a bank-padded LDS agg tile [16][72]; syncthreads;
// then wave w computes output slab nt=w (16 cols) with 4 MFMAs. kt 2-3
// A-frags (the h part) read directly from hin (no staging).
// r16 (16 waves/block), r17 (paired ILP), r18 (64-wide idx) all regressed:
// occupancy/VALU payback. This shape is the measured local optimum.
__global__ __launch_bounds__(256) void fused_layer_kernel(
        const ushort_t* __restrict__ hin, ushort_t* __restrict__ hout,
        const int* __restrict__ rowstart, const int* __restrict__ csr,
        const ushort_t* __restrict__ WcatT, const float* __restrict__ b,
        int relu) {
    __shared__ ushort_t As[16][72];   // agg rows; stride 144B -> bank-spread
    const int lane = threadIdx.x & 63;
    const int wid = threadIdx.x >> 6;
    const int l4 = lane & 15;             // feature quad
    const int q = lane >> 4;              // edge sub-slot 0..3
    const int node0 = blockIdx.x * 16;

    // ---- gather phase: wave wid owns rows wid*4 .. wid*4+3 ----
    for (int i = 0; i < 4; ++i) {
        const int row = wid * 4 + i;
        const int node = __builtin_amdgcn_readfirstlane(node0 + row);
        const int e0 = rowstart[node], e1 = rowstart[node + 1];
        float ax[4], ay[4], az[4], aw[4];
#pragma unroll
        for (int j = 0; j < 4; ++j) { ax[j] = 0.f; ay[j] = 0.f; az[j] = 0.f; aw[j] = 0.f; }
        int e = e0;
        for (; e + 16 <= e1; e += 16) {
            int idx = csr[e + (lane & 15)];   // one coalesced 64B line
#pragma unroll
            for (int j = 0; j < 4; ++j) {
                int s = __shfl(idx, 4 * j + q);
                uint2 rp = *(const uint2*)&hin[(size_t)s * 64 + 4 * l4];
                ax[j] += __uint_as_float(rp.x << 16);
                ay[j] += __uint_as_float(rp.x & 0xFFFF0000u);
                az[j] += __uint_as_float(rp.y << 16);
                aw[j] += __uint_as_float(rp.y & 0xFFFF0000u);
            }
        }
        if (e < e1) {                         // tail: ONE clamped idx load
            const int rem = e1 - e;
            const int last = e1 - 1;
            int idx = csr[min(e + (lane & 15), last)];
#pragma unroll
            for (int j = 0; j < 4; ++j) {
                int slot = 4 * j + q;
                int s = __shfl(idx, slot);    // clamped -> valid node
                uint2 rp = *(const uint2*)&hin[(size_t)s * 64 + 4 * l4];
                bool ok = slot < rem;
                ax[j] += ok ? __uint_as_float(rp.x << 16) : 0.f;
                ay[j] += ok ? __uint_as_float(rp.x & 0xFFFF0000u) : 0.f;
                az[j] += ok ? __uint_as_float(rp.y << 16) : 0.f;
                aw[j] += ok ? __uint_as_float(rp.y & 0xFFFF0000u) : 0.f;
            }
        }
        float fx = (ax[0] + ax[1]) + (ax[2] + ax[3]);
        float fy = (ay[0] + ay[1]) + (ay[2] + ay[3]);
        float fz = (az[0] + az[1]) + (az[2] + az[3]);
        float fw = (aw[0] + aw[1]) + (aw[2] + aw[3]);
        fx += __shfl_xor(fx, 16); fx += __shfl_xor(fx, 32);
        fy += __shfl_xor(fy, 16); fy += __shfl_xor(fy, 32);
        fz += __shfl_xor(fz, 16); fz += __shfl_xor(fz, 32);
        fw += __shfl_xor(fw, 16); fw += __shfl_xor(fw, 32);
        if (lane < 16) {
            uint2 ap;
            ap.x = (unsigned)f2bf(fx) | ((unsigned)f2bf(fy) << 16);
            ap.y = (unsigned)f2bf(fz) | ((unsigned)f2bf(fw) << 16);
            *(uint2*)&As[row][l4 * 4] = ap;
        }
    }
    __syncthreads();

    // ---- GEMM phase: wave wid computes slab nt = wid (cols wid*16..+15) ----
    const int col = lane & 15;
    const int grp = lane >> 4;
    bf16x8 bf[4];
#pragma unroll
    for (int kt = 0; kt < 4; ++kt)
        bf[kt] = *(const bf16x8*)&WcatT[(wid * 16 + col) * 128 + kt * 32 + grp * 8];
    const float bj = b[wid * 16 + col];

    const ushort_t* ha = hin + (size_t)(node0 + col) * 64 + grp * 8;
    f32x4 acc = {0.f, 0.f, 0.f, 0.f};
#pragma unroll
    for (int kt = 0; kt < 4; ++kt) {
        bf16x8 a = (kt < 2) ? *(const bf16x8*)&As[col][kt * 32 + grp * 8]
                            : *(const bf16x8*)(ha + (kt - 2) * 32);
        acc = __builtin_amdgcn_mfma_f32_16x16x32_bf16(a, bf[kt], acc, 0, 0, 0);
    }
    const int c = wid * 16 + col;
#pragma unroll
    for (int r = 0; r < 4; ++r) {
        int row = grp * 4 + r;
        float v = acc[r] + bj;
        if (relu) v = fmaxf(v, 0.f);
        hout[(size_t)(node0 + row) * 64 + c] = f2bf(v);
    }
}

// ---------------------------------------------------------------------------
// Mean-pool per graph (r10): 8-row unrolled loads.
__global__ void pool_kernel(const ushort_t* __restrict__ h3, const int* __restrict__ batch,
                            float* __restrict__ pool, float* __restrict__ cnt) {
    const int lane = threadIdx.x & 63;
    const int gw = (blockIdx.x * blockDim.x + threadIdx.x) >> 6;
    const int nW = (gridDim.x * blockDim.x) >> 6;
    const int chunk = (N_NODES + nW - 1) / nW;
    int n0 = gw * chunk;
    int n1 = n0 + chunk; if (n1 > N_NODES) n1 = N_NODES;
    if (n0 >= N_NODES) return;
    float acc = 0.f;
    int cur = batch[n0];
    int cl = 0;
#define POOL_FLUSH() do { atomicAdd(&pool[cur * 64 + lane], acc); \
        if (lane == 0) atomicAdd(&cnt[cur], (float)cl); acc = 0.f; cl = 0; } while (0)
    int n = n0;
    for (; n + 8 <= n1; n += 8) {
        float v0 = bf2f(h3[(size_t)(n + 0) * 64 + lane]);
        float v1 = bf2f(h3[(size_t)(n + 1) * 64 + lane]);
        float v2 = bf2f(h3[(size_t)(n + 2) * 64 + lane]);
        float v3 = bf2f(h3[(size_t)(n + 3) * 64 + lane]);
        float v4 = bf2f(h3[(size_t)(n + 4) * 64 + lane]);
        float v5 = bf2f(h3[(size_t)(n + 5) * 64 + lane]);
        float v6 = bf2f(h3[(size_t)(n + 6) * 64 + lane]);
        float v7 = bf2f(h3[(size_t)(n + 7) * 64 + lane]);
        int g0 = batch[n + 0], g1 = batch[n + 1], g2 = batch[n + 2], g3 = batch[n + 3];
        int g4 = batch[n + 4], g5 = batch[n + 5], g6 = batch[n + 6], g7 = batch[n + 7];
        if (g0 != cur) { POOL_FLUSH(); cur = g0; } acc += v0; cl++;
        if (g1 != cur) { POOL_FLUSH(); cur = g1; } acc += v1; cl++;
        if (g2 != cur) { POOL_FLUSH(); cur = g2; } acc += v2; cl++;
        if (g3 != cur) { POOL_FLUSH(); cur = g3; } acc += v3; cl++;
        if (g4 != cur) { POOL_FLUSH(); cur = g4; } acc += v4; cl++;
        if (g5 != cur) { POOL_FLUSH(); cur = g5; } acc += v5; cl++;
        if (g6 != cur) { POOL_FLUSH(); cur = g6; } acc += v6; cl++;
        if (g7 != cur) { POOL_FLUSH(); cur = g7; } acc += v7; cl++;
    }
    for (; n < n1; ++n) {
        int g = batch[n];
        if (g != cur) { POOL_FLUSH(); cur = g; }
        acc += bf2f(h3[(size_t)n * 64 + lane]);
        cl++;
    }
    atomicAdd(&pool[cur * 64 + lane], acc);
    if (lane == 0) atomicAdd(&cnt[cur], (float)cl);
#undef POOL_FLUSH
}

// Final head
__global__ void head_kernel(const float* __restrict__ pool, const float* __restrict__ cnt,
                            const float* __restrict__ linW, const float* __restrict__ linb,
                            float* __restrict__ out) {
    int g = threadIdx.x >> 1;
    int c = threadIdx.x & 1;
    if (g < N_GRAPHS) {
        float inv = 1.0f / fmaxf(cnt[g], 1.0f);
        float acc = linb[c];
        for (int j = 0; j < 64; ++j) acc += pool[g * 64 + j] * inv * linW[j * 2 + c];
        out[g * 2 + c] = acc;
    }
}

// ---------------------------------------------------------------------------
extern "C" void kernel_launch(void* const* d_in, const int* in_sizes, int n_in,
                              void* d_out, int out_size, void* d_ws, size_t ws_size,
                              hipStream_t stream) {
    const float* x = (const float*)d_in[0];
    const int* edge_index = (const int*)d_in[1];
    const int* batch = (const int*)d_in[2];
    const float* bn_gamma = (const float*)d_in[3];
    const float* bn_beta = (const float*)d_in[4];
    const float* bn_mean = (const float*)d_in[5];
    const float* bn_var = (const float*)d_in[6];
    const float* W1_rel = (const float*)d_in[7];
    const float* b1_rel = (const float*)d_in[8];
    const float* W1_root = (const float*)d_in[9];
    const float* W2_rel = (const float*)d_in[10];
    const float* b2_rel = (const float*)d_in[11];
    const float* W2_root = (const float*)d_in[12];
    const float* W3_rel = (const float*)d_in[13];
    const float* b3_rel = (const float*)d_in[14];
    const float* W3_root = (const float*)d_in[15];
    const float* lin_W = (const float*)d_in[16];
    const float* lin_b = (const float*)d_in[17];
    float* out = (float*)d_out;

    const int* e_src = edge_index;
    const int* e_dst = edge_index + N_EDGES;

    // workspace layout (16B-aligned sections)
    ushort_t* h1 = (ushort_t*)d_ws;             // 5.12M bf16 = 10.24MB
    ushort_t* h2 = h1 + 5120000;                // 5.12M bf16 = 10.24MB
    float* pool = (float*)(h2 + 5120000);       // 4096 f32
    float* cnt = pool + 4096;                   // 64
    int* bcursor = (int*)(cnt + 64);            // 320
    int* rowstart = bcursor + 640;              // 80016 (padded)
    int* csr = rowstart + 80016;                // 1280000
    ushort_t* WcatT2 = (ushort_t*)(csr + 1280000); // 8192 bf16
    ushort_t* WcatT3 = WcatT2 + 8192;              // 8192 bf16
    unsigned* pairs = (unsigned*)h1;            // NBUCK*BCAP*4B = 10.02MB <= h1
    ushort_t* h3 = h1;                          // alias: h1 dead once h2 computed

    // Weight prep + zero-init (bcursor/pool/cnt)
    wprep_kernel<<<64, 256, 0, stream>>>(W2_rel, W2_root, W3_rel, W3_root,
                                         WcatT2, WcatT3, bcursor, pool, cnt);

    // CSR build (bucketed counting sort; scan folded into csr_build)
    bucket_kernel<<<(N_EDGES + 4095) / 4096, 256, 0, stream>>>(
        e_src, e_dst, pairs, bcursor);
    csr_build_kernel<<<NBUCK, 256, 0, stream>>>(pairs, bcursor, rowstart, csr);

    // Layer 1 (BN folded, grid-stride): h1 = relu(conv(bn(x)))
    layer1_kernel<<<512, 1024, 0, stream>>>(x, h1, rowstart, csr, W1_rel, W1_root,
                                            b1_rel, bn_gamma, bn_beta, bn_mean, bn_var);

    // Layer 2 (fused gather+GEMM): h2 = relu(conv(h1))
    fused_layer_kernel<<<N_NODES / 16, 256, 0, stream>>>(
        h1, h2, rowstart, csr, WcatT2, b2_rel, 1);
    // Layer 3 (fused): h3 = conv(h2)   (h3 aliases h1)
    fused_layer_kernel<<<N_NODES / 16, 256, 0, stream>>>(
        h2, h3, rowstart, csr, WcatT3, b3_rel, 0);

    // Pool + head
    pool_kernel<<<256, 256, 0, stream>>>(h3, batch, pool, cnt);
    head_kernel<<<1, 128, 0, stream>>>(pool, cnt, lin_W, lin_b, out);
}

// Round 21
// 157.586 us; speedup vs baseline: 1.1161x; 1.0305x over previous
//
#include <hip/hip_runtime.h>
#include <hip/hip_bf16.h>

#define N_NODES 80000
#define N_EDGES 1280000
#define N_FEAT 4
#define HIDDEN 64
#define N_GRAPHS 64
#define BN_EPS 1e-5f

#define NBUCK 313          // ceil(80000 / 256); bucket b covers nodes [b*256, b*256+256)
#define BCAP 8000          // per-bucket capacity (mean 4090, sigma ~64 -> safe)

typedef unsigned short ushort_t;
typedef __attribute__((ext_vector_type(8))) short bf16x8;
typedef __attribute__((ext_vector_type(4))) float f32x4;

__device__ __forceinline__ float bf2f(ushort_t v) {
    return __uint_as_float(((unsigned)v) << 16);
}
__device__ __forceinline__ ushort_t f2bf(float f) {
    unsigned u = __float_as_uint(f);
    u += 0x7FFFu + ((u >> 16) & 1u);
    return (ushort_t)(u >> 16);
}

// ---------------------------------------------------------------------------
// Weight prep (layers 2+3) + zero-init of bcursor/pool/cnt
__global__ void wprep_kernel(const float* __restrict__ W2_rel,
                             const float* __restrict__ W2_root,
                             const float* __restrict__ W3_rel,
                             const float* __restrict__ W3_root,
                             ushort_t* __restrict__ WcatT2,
                             ushort_t* __restrict__ WcatT3,
                             int* __restrict__ bcursor,
                             float* __restrict__ pool,
                             float* __restrict__ cnt) {
    int i = blockIdx.x * blockDim.x + threadIdx.x;   // 64*256 = 16384 = 2*8192
    int which = i >= 64 * 128;
    int j = i & (64 * 128 - 1);
    int n = j >> 7, k = j & 127;
    const float* Wr = which ? W3_rel : W2_rel;
    const float* Wo = which ? W3_root : W2_root;
    ushort_t* Wc = which ? WcatT3 : WcatT2;
    float w = (k < 64) ? Wr[k * 64 + n] : Wo[(k - 64) * 64 + n];
    Wc[j] = f2bf(w);
    if (i < 4096) pool[i] = 0.f;
    else if (i < 4160) cnt[i - 4096] = 0.f;
    else if (i < 4160 + NBUCK) bcursor[i - 4160] = 0;
}

// ---------------------------------------------------------------------------
// Bucketed counting sort (r13: int4 vectorized edge loads; packed pairs)
__global__ __launch_bounds__(256) void bucket_kernel(
        const int* __restrict__ src, const int* __restrict__ dst,
        unsigned* __restrict__ pairs, int* __restrict__ bcursor) {
    __shared__ int hist[NBUCK];
    __shared__ int base[NBUCK];
    for (int i = threadIdx.x; i < NBUCK; i += 256) hist[i] = 0;
    __syncthreads();
    int d[16], r[16];
#pragma unroll
    for (int g = 0; g < 4; ++g) {
        int e = blockIdx.x * 4096 + g * 1024 + threadIdx.x * 4;
        if (e + 4 <= N_EDGES) {
            int4 dd = *(const int4*)&dst[e];
            d[g * 4 + 0] = dd.x; d[g * 4 + 1] = dd.y;
            d[g * 4 + 2] = dd.z; d[g * 4 + 3] = dd.w;
            r[g * 4 + 0] = atomicAdd(&hist[dd.x >> 8], 1);
            r[g * 4 + 1] = atomicAdd(&hist[dd.y >> 8], 1);
            r[g * 4 + 2] = atomicAdd(&hist[dd.z >> 8], 1);
            r[g * 4 + 3] = atomicAdd(&hist[dd.w >> 8], 1);
        } else {
            d[g * 4] = -1;
        }
    }
    __syncthreads();
    for (int i = threadIdx.x; i < NBUCK; i += 256) {
        int c = hist[i];
        base[i] = c ? atomicAdd(&bcursor[i], c) : 0;
    }
    __syncthreads();
#pragma unroll
    for (int g = 0; g < 4; ++g) {
        int e = blockIdx.x * 4096 + g * 1024 + threadIdx.x * 4;
        if (e + 4 <= N_EDGES) {
            int4 ss = *(const int4*)&src[e];
            int sv[4] = {ss.x, ss.y, ss.z, ss.w};
#pragma unroll
            for (int k = 0; k < 4; ++k) {
                int dk = d[g * 4 + k];
                int b = dk >> 8;
                int pos = base[b] + r[g * 4 + k];
                if (pos < BCAP)
                    pairs[(size_t)b * BCAP + pos] =
                        (unsigned)sv[k] | (((unsigned)dk & 255u) << 17);
            }
        }
    }
}

// ---------------------------------------------------------------------------
// csr_build (r13: uint4 pair reads; inline base computation)
__global__ __launch_bounds__(256) void csr_build_kernel(
        const unsigned* __restrict__ pairs, const int* __restrict__ bcursor,
        int* __restrict__ rowstart, int* __restrict__ csr) {
    __shared__ int degl[256];
    __shared__ int pref[256];
    __shared__ int curs[256];
    const int b = blockIdx.x;
    const int t = threadIdx.x;
    int partial = 0;
    for (int i = t; i < b; i += 256) partial += min(bcursor[i], BCAP);
    pref[t] = partial;
    __syncthreads();
    for (int off = 128; off > 0; off >>= 1) {
        if (t < off) pref[t] += pref[t + off];
        __syncthreads();
    }
    const int base = pref[0];
    const int cntb = min(bcursor[b], BCAP);
    __syncthreads();
    degl[t] = 0;
    __syncthreads();
    const unsigned* pb = pairs + (size_t)b * BCAP;
    for (int i = t * 4; i < cntb; i += 1024) {
        if (i + 4 <= cntb) {
            uint4 p4 = *(const uint4*)&pb[i];
            atomicAdd(&degl[p4.x >> 17], 1);
            atomicAdd(&degl[p4.y >> 17], 1);
            atomicAdd(&degl[p4.z >> 17], 1);
            atomicAdd(&degl[p4.w >> 17], 1);
        } else {
            for (int k = i; k < cntb; ++k) atomicAdd(&degl[pb[k] >> 17], 1);
        }
    }
    __syncthreads();
    int v = degl[t];
    pref[t] = v;
    __syncthreads();
    for (int off = 1; off < 256; off <<= 1) {
        int u = (t >= off) ? pref[t - off] : 0;
        __syncthreads();
        pref[t] += u;
        __syncthreads();
    }
    int excl = pref[t] - v;
    int node = b * 256 + t;
    if (node < N_NODES) rowstart[node] = base + excl;
    if (b == NBUCK - 1 && t == 255) rowstart[N_NODES] = base + cntb;
    curs[t] = excl;
    __syncthreads();
    for (int i = t * 4; i < cntb; i += 1024) {
        if (i + 4 <= cntb) {
            uint4 p4 = *(const uint4*)&pb[i];
            unsigned pv[4] = {p4.x, p4.y, p4.z, p4.w};
#pragma unroll
            for (int k = 0; k < 4; ++k) {
                int pos = atomicAdd(&curs[pv[k] >> 17], 1);
                csr[base + pos] = (int)(pv[k] & 0x1FFFFu);
            }
        } else {
            for (int k = i; k < cntb; ++k) {
                unsigned p = pb[k];
                int pos = atomicAdd(&curs[p >> 17], 1);
                csr[base + pos] = (int)(p & 0x1FFFFu);
            }
        }
    }
}

// ---------------------------------------------------------------------------
// Layer 1 (in=4, out=64), BN folded — grid-stride (r13 form).
__global__ __launch_bounds__(1024) void layer1_kernel(
        const float* __restrict__ x, ushort_t* __restrict__ h1,
        const int* __restrict__ rowstart, const int* __restrict__ csr,
        const float* __restrict__ Wrel, const float* __restrict__ Wroot,
        const float* __restrict__ b,
        const float* __restrict__ gamma, const float* __restrict__ beta,
        const float* __restrict__ mean, const float* __restrict__ var) {
    const int lane = threadIdx.x & 63;
    const int wid = threadIdx.x >> 6;
    float scale[4], shift[4];
#pragma unroll
    for (int k = 0; k < 4; ++k) {
        float sc = gamma[k] * rsqrtf(var[k] + BN_EPS);
        scale[k] = sc;
        shift[k] = beta[k] - mean[k] * sc;
    }
    float wrel2[4], wroot2[4];
    float crel = 0.f, croot = 0.f;
#pragma unroll
    for (int k = 0; k < 4; ++k) {
        float wr = Wrel[k * 64 + lane], wo = Wroot[k * 64 + lane];
        wrel2[k] = scale[k] * wr;  crel += shift[k] * wr;
        wroot2[k] = scale[k] * wo; croot += shift[k] * wo;
    }
    const float bj = b[lane] + croot;
    const int sub = lane >> 2;
    const int f = lane & 3;
    const int nW = gridDim.x * 16;
    for (int n0 = blockIdx.x * 16 + wid; n0 < N_NODES; n0 += nW) {
        const int node = __builtin_amdgcn_readfirstlane(n0);
        const int e0 = rowstart[node], e1 = rowstart[node + 1];
        const float deg = (float)(e1 - e0);
        float part = 0.f;
        for (int e = e0 + sub; e < e1; e += 16) {
            int s = csr[e];
            part += x[s * 4 + f];
        }
        part += __shfl_xor(part, 4);
        part += __shfl_xor(part, 8);
        part += __shfl_xor(part, 16);
        part += __shfl_xor(part, 32);
        float a0 = __shfl(part, 0), a1 = __shfl(part, 1);
        float a2 = __shfl(part, 2), a3 = __shfl(part, 3);
        float x0 = x[node * 4 + 0], x1 = x[node * 4 + 1];
        float x2 = x[node * 4 + 2], x3 = x[node * 4 + 3];
        float out = bj + deg * crel
                  + a0 * wrel2[0] + a1 * wrel2[1] + a2 * wrel2[2] + a3 * wrel2[3]
                  + x0 * wroot2[0] + x1 * wroot2[1] + x2 * wroot2[2] + x3 * wroot2[3];
        h1[(size_t)node * 64 + lane] = f2bf(fmaxf(out, 0.f));
    }
}

// ---------------------------------------------------------------------------
// Fused layer v5 (r20): r15 structure + FIRST-IDX PREFETCH across the 4
// serial node-gathers. e0/e1 for all 4 rows preloaded (SGPR); node i+1's
// first idx line (unified clamped form, valid for both full-16 and tail)
// is issued during node i's row loads -> removes 3 of 4 idx latencies from
// the chain at ~+1 VGPR (no accumulator duplication, unlike r17).
__global__ __launch_bounds__(256) void fused_layer_kernel(
        const ushort_t* __restrict__ hin, ushort_t* __restrict__ hout,
        const int* __restrict__ rowstart, const int* __restrict__ csr,
        const ushort_t* __restrict__ WcatT, const float* __restrict__ b,
        int relu) {
    __shared__ ushort_t As[16][72];   // agg rows; stride 144B -> bank-spread
    const int lane = threadIdx.x & 63;
    const int wid = threadIdx.x >> 6;
    const int l4 = lane & 15;             // feature quad
    const int q = lane >> 4;              // edge sub-slot 0..3
    const int node0 = blockIdx.x * 16;

    // preload row extents for this wave's 4 nodes (scalar)
    int e0s[4], e1s[4];
#pragma unroll
    for (int i = 0; i < 4; ++i) {
        const int node = __builtin_amdgcn_readfirstlane(node0 + wid * 4 + i);
        e0s[i] = rowstart[node];
        e1s[i] = rowstart[node + 1];
    }
    // unified clamped first-idx: valid whether the first step is full or tail
    int idxNext = csr[min(e0s[0] + (lane & 15), max(e1s[0] - 1, e0s[0]))];

    // ---- gather phase: wave wid owns rows wid*4 .. wid*4+3 ----
    for (int i = 0; i < 4; ++i) {
        const int row = wid * 4 + i;
        const int e0 = e0s[i], e1 = e1s[i];
        int idx = idxNext;                 // prefetched first line of this node
        if (i < 3)                         // issue next node's first idx NOW
            idxNext = csr[min(e0s[i + 1] + (lane & 15), max(e1s[i + 1] - 1, e0s[i + 1]))];
        float ax[4], ay[4], az[4], aw[4];
#pragma unroll
        for (int j = 0; j < 4; ++j) { ax[j] = 0.f; ay[j] = 0.f; az[j] = 0.f; aw[j] = 0.f; }
        int e = e0;
        if (e + 16 <= e1) {
            // first full step consumes the prefetched idx
#pragma unroll
            for (int j = 0; j < 4; ++j) {
                int s = __shfl(idx, 4 * j + q);
                uint2 rp = *(const uint2*)&hin[(size_t)s * 64 + 4 * l4];
                ax[j] += __uint_as_float(rp.x << 16);
                ay[j] += __uint_as_float(rp.x & 0xFFFF0000u);
                az[j] += __uint_as_float(rp.y << 16);
                aw[j] += __uint_as_float(rp.y & 0xFFFF0000u);
            }
            e += 16;
            // subsequent full steps load their own idx
            for (; e + 16 <= e1; e += 16) {
                idx = csr[e + (lane & 15)];
#pragma unroll
                for (int j = 0; j < 4; ++j) {
                    int s = __shfl(idx, 4 * j + q);
                    uint2 rp = *(const uint2*)&hin[(size_t)s * 64 + 4 * l4];
                    ax[j] += __uint_as_float(rp.x << 16);
                    ay[j] += __uint_as_float(rp.x & 0xFFFF0000u);
                    az[j] += __uint_as_float(rp.y << 16);
                    aw[j] += __uint_as_float(rp.y & 0xFFFF0000u);
                }
            }
            if (e < e1) {                  // tail after full steps: own clamped idx
                const int rem = e1 - e;
                idx = csr[min(e + (lane & 15), e1 - 1)];
#pragma unroll
                for (int j = 0; j < 4; ++j) {
                    int slot = 4 * j + q;
                    int s = __shfl(idx, slot);
                    uint2 rp = *(const uint2*)&hin[(size_t)s * 64 + 4 * l4];
                    bool ok = slot < rem;
                    ax[j] += ok ? __uint_as_float(rp.x << 16) : 0.f;
                    ay[j] += ok ? __uint_as_float(rp.x & 0xFFFF0000u) : 0.f;
                    az[j] += ok ? __uint_as_float(rp.y << 16) : 0.f;
                    aw[j] += ok ? __uint_as_float(rp.y & 0xFFFF0000u) : 0.f;
                }
            }
        } else if (e < e1) {
            // deg 1..15: the prefetched idx IS the tail
            const int rem = e1 - e;
#pragma unroll
            for (int j = 0; j < 4; ++j) {
                int slot = 4 * j + q;
                int s = __shfl(idx, slot);
                uint2 rp = *(const uint2*)&hin[(size_t)s * 64 + 4 * l4];
                bool ok = slot < rem;
                ax[j] += ok ? __uint_as_float(rp.x << 16) : 0.f;
                ay[j] += ok ? __uint_as_float(rp.x & 0xFFFF0000u) : 0.f;
                az[j] += ok ? __uint_as_float(rp.y << 16) : 0.f;
                aw[j] += ok ? __uint_as_float(rp.y & 0xFFFF0000u) : 0.f;
            }
        }
        float fx = (ax[0] + ax[1]) + (ax[2] + ax[3]);
        float fy = (ay[0] + ay[1]) + (ay[2] + ay[3]);
        float fz = (az[0] + az[1]) + (az[2] + az[3]);
        float fw = (aw[0] + aw[1]) + (aw[2] + aw[3]);
        fx += __shfl_xor(fx, 16); fx += __shfl_xor(fx, 32);
        fy += __shfl_xor(fy, 16); fy += __shfl_xor(fy, 32);
        fz += __shfl_xor(fz, 16); fz += __shfl_xor(fz, 32);
        fw += __shfl_xor(fw, 16); fw += __shfl_xor(fw, 32);
        if (lane < 16) {
            uint2 ap;
            ap.x = (unsigned)f2bf(fx) | ((unsigned)f2bf(fy) << 16);
            ap.y = (unsigned)f2bf(fz) | ((unsigned)f2bf(fw) << 16);
            *(uint2*)&As[row][l4 * 4] = ap;
        }
    }
    __syncthreads();

    // ---- GEMM phase: wave wid computes slab nt = wid (cols wid*16..+15) ----
    const int col = lane & 15;
    const int grp = lane >> 4;
    bf16x8 bf[4];
#pragma unroll
    for (int kt = 0; kt < 4; ++kt)
        bf[kt] = *(const bf16x8*)&WcatT[(wid * 16 + col) * 128 + kt * 32 + grp * 8];
    const float bj = b[wid * 16 + col];

    const ushort_t* ha = hin + (size_t)(node0 + col) * 64 + grp * 8;
    f32x4 acc = {0.f, 0.f, 0.f, 0.f};
#pragma unroll
    for (int kt = 0; kt < 4; ++kt) {
        bf16x8 a = (kt < 2) ? *(const bf16x8*)&As[col][kt * 32 + grp * 8]
                            : *(const bf16x8*)(ha + (kt - 2) * 32);
        acc = __builtin_amdgcn_mfma_f32_16x16x32_bf16(a, bf[kt], acc, 0, 0, 0);
    }
    const int c = wid * 16 + col;
#pragma unroll
    for (int r = 0; r < 4; ++r) {
        int row = grp * 4 + r;
        float v = acc[r] + bj;
        if (relu) v = fmaxf(v, 0.f);
        hout[(size_t)(node0 + row) * 64 + c] = f2bf(v);
    }
}

// ---------------------------------------------------------------------------
// Mean-pool per graph (r10): 8-row unrolled loads.
__global__ void pool_kernel(const ushort_t* __restrict__ h3, const int* __restrict__ batch,
                            float* __restrict__ pool, float* __restrict__ cnt) {
    const int lane = threadIdx.x & 63;
    const int gw = (blockIdx.x * blockDim.x + threadIdx.x) >> 6;
    const int nW = (gridDim.x * blockDim.x) >> 6;
    const int chunk = (N_NODES + nW - 1) / nW;
    int n0 = gw * chunk;
    int n1 = n0 + chunk; if (n1 > N_NODES) n1 = N_NODES;
    if (n0 >= N_NODES) return;
    float acc = 0.f;
    int cur = batch[n0];
    int cl = 0;
#define POOL_FLUSH() do { atomicAdd(&pool[cur * 64 + lane], acc); \
        if (lane == 0) atomicAdd(&cnt[cur], (float)cl); acc = 0.f; cl = 0; } while (0)
    int n = n0;
    for (; n + 8 <= n1; n += 8) {
        float v0 = bf2f(h3[(size_t)(n + 0) * 64 + lane]);
        float v1 = bf2f(h3[(size_t)(n + 1) * 64 + lane]);
        float v2 = bf2f(h3[(size_t)(n + 2) * 64 + lane]);
        float v3 = bf2f(h3[(size_t)(n + 3) * 64 + lane]);
        float v4 = bf2f(h3[(size_t)(n + 4) * 64 + lane]);
        float v5 = bf2f(h3[(size_t)(n + 5) * 64 + lane]);
        float v6 = bf2f(h3[(size_t)(n + 6) * 64 + lane]);
        float v7 = bf2f(h3[(size_t)(n + 7) * 64 + lane]);
        int g0 = batch[n + 0], g1 = batch[n + 1], g2 = batch[n + 2], g3 = batch[n + 3];
        int g4 = batch[n + 4], g5 = batch[n + 5], g6 = batch[n + 6], g7 = batch[n + 7];
        if (g0 != cur) { POOL_FLUSH(); cur = g0; } acc += v0; cl++;
        if (g1 != cur) { POOL_FLUSH(); cur = g1; } acc += v1; cl++;
        if (g2 != cur) { POOL_FLUSH(); cur = g2; } acc += v2; cl++;
        if (g3 != cur) { POOL_FLUSH(); cur = g3; } acc += v3; cl++;
        if (g4 != cur) { POOL_FLUSH(); cur = g4; } acc += v4; cl++;
        if (g5 != cur) { POOL_FLUSH(); cur = g5; } acc += v5; cl++;
        if (g6 != cur) { POOL_FLUSH(); cur = g6; } acc += v6; cl++;
        if (g7 != cur) { POOL_FLUSH(); cur = g7; } acc += v7; cl++;
    }
    for (; n < n1; ++n) {
        int g = batch[n];
        if (g != cur) { POOL_FLUSH(); cur = g; }
        acc += bf2f(h3[(size_t)n * 64 + lane]);
        cl++;
    }
    atomicAdd(&pool[cur * 64 + lane], acc);
    if (lane == 0) atomicAdd(&cnt[cur], (float)cl);
#undef POOL_FLUSH
}

// Final head
__global__ void head_kernel(const float* __restrict__ pool, const float* __restrict__ cnt,
                            const float* __restrict__ linW, const float* __restrict__ linb,
                            float* __restrict__ out) {
    int g = threadIdx.x >> 1;
    int c = threadIdx.x & 1;
    if (g < N_GRAPHS) {
        float inv = 1.0f / fmaxf(cnt[g], 1.0f);
        float acc = linb[c];
        for (int j = 0; j < 64; ++j) acc += pool[g * 64 + j] * inv * linW[j * 2 + c];
        out[g * 2 + c] = acc;
    }
}

// ---------------------------------------------------------------------------
extern "C" void kernel_launch(void* const* d_in, const int* in_sizes, int n_in,
                              void* d_out, int out_size, void* d_ws, size_t ws_size,
                              hipStream_t stream) {
    const float* x = (const float*)d_in[0];
    const int* edge_index = (const int*)d_in[1];
    const int* batch = (const int*)d_in[2];
    const float* bn_gamma = (const float*)d_in[3];
    const float* bn_beta = (const float*)d_in[4];
    const float* bn_mean = (const float*)d_in[5];
    const float* bn_var = (const float*)d_in[6];
    const float* W1_rel = (const float*)d_in[7];
    const float* b1_rel = (const float*)d_in[8];
    const float* W1_root = (const float*)d_in[9];
    const float* W2_rel = (const float*)d_in[10];
    const float* b2_rel = (const float*)d_in[11];
    const float* W2_root = (const float*)d_in[12];
    const float* W3_rel = (const float*)d_in[13];
    const float* b3_rel = (const float*)d_in[14];
    const float* W3_root = (const float*)d_in[15];
    const float* lin_W = (const float*)d_in[16];
    const float* lin_b = (const float*)d_in[17];
    float* out = (float*)d_out;

    const int* e_src = edge_index;
    const int* e_dst = edge_index + N_EDGES;

    // workspace layout (16B-aligned sections)
    ushort_t* h1 = (ushort_t*)d_ws;             // 5.12M bf16 = 10.24MB
    ushort_t* h2 = h1 + 5120000;                // 5.12M bf16 = 10.24MB
    float* pool = (float*)(h2 + 5120000);       // 4096 f32
    float* cnt = pool + 4096;                   // 64
    int* bcursor = (int*)(cnt + 64);            // 320
    int* rowstart = bcursor + 640;              // 80016 (padded)
    int* csr = rowstart + 80016;                // 1280000
    ushort_t* WcatT2 = (ushort_t*)(csr + 1280000); // 8192 bf16
    ushort_t* WcatT3 = WcatT2 + 8192;              // 8192 bf16
    unsigned* pairs = (unsigned*)h1;            // NBUCK*BCAP*4B = 10.02MB <= h1
    ushort_t* h3 = h1;                          // alias: h1 dead once h2 computed

    // Weight prep + zero-init (bcursor/pool/cnt)
    wprep_kernel<<<64, 256, 0, stream>>>(W2_rel, W2_root, W3_rel, W3_root,
                                         WcatT2, WcatT3, bcursor, pool, cnt);

    // CSR build (bucketed counting sort; scan folded into csr_build)
    bucket_kernel<<<(N_EDGES + 4095) / 4096, 256, 0, stream>>>(
        e_src, e_dst, pairs, bcursor);
    csr_build_kernel<<<NBUCK, 256, 0, stream>>>(pairs, bcursor, rowstart, csr);

    // Layer 1 (BN folded, grid-stride): h1 = relu(conv(bn(x)))
    layer1_kernel<<<512, 1024, 0, stream>>>(x, h1, rowstart, csr, W1_rel, W1_root,
                                            b1_rel, bn_gamma, bn_beta, bn_mean, bn_var);

    // Layer 2 (fused gather+GEMM, idx prefetch): h2 = relu(conv(h1))
    fused_layer_kernel<<<N_NODES / 16, 256, 0, stream>>>(
        h1, h2, rowstart, csr, WcatT2, b2_rel, 1);
    // Layer 3 (fused): h3 = conv(h2)   (h3 aliases h1)
    fused_layer_kernel<<<N_NODES / 16, 256, 0, stream>>>(
        h2, h3, rowstart, csr, WcatT3, b3_rel, 0);

    // Pool + head
    pool_kernel<<<256, 256, 0, stream>>>(h3, batch, pool, cnt);
    head_kernel<<<1, 128, 0, stream>>>(pool, cnt, lin_W, lin_b, out);
}